// Round 8
// baseline (25108.273 us; speedup 1.0000x reference)
//
#include <hip/hip_runtime.h>

// DCRNN encoder-decoder on MI355X (gfx950), ONE persistent kernel.
// gso (8192^2 dense fp32) is ~0.2% dense (~17 nnz/row, zeros exact): ELL once.
// R3: cg::grid.sync = 175us/sync (system acq_rel + 1024 spinners).
// R5: agent acq_rel barrier = 106us/sync — buffer_wbl2+buffer_inv per block
//     nukes per-XCD L2 every barrier (41 MB refetch/barrier, VALUBusy 4%).
// R6/R7/R8: coherence-FREE barrier. Cross-barrier feature arrays use relaxed
//     SYSTEM-scope atomic ld/st (compile to sc0 sc1 -> memory-side Infinity
//     Cache, always coherent; no wbl2/inv anywhere). Read-only ELL/weights/x
//     stay L2-cached forever. Barrier = relaxed counters; release = the
//     vmcnt(0) drain __syncthreads performs before s_barrier.
//     h/u/r*h/hop-results/x-in live in REGISTERS per wave across all cells.

#define NV  8192
#define TT  24
#define CAP 64                  // ELL capacity (row degree ~Poisson(17))
#define BLK 512                 // 8 waves/block
#define GRD 256                 // 1 block/CU -> co-resident
#define WPB (BLK / 64)
#define NWAVES (GRD * WPB)      // 2048
#define NPW (NV / NWAVES)       // 4 nodes per wave
#define NGROUPS 32
#define BPG (GRD / NGROUPS)     // 8 blocks per barrier group
#define BARSZ 1056              // root + 32 group counters at 128B stride

__device__ __forceinline__ float cload(const float* p) {
    return __hip_atomic_load(p, __ATOMIC_RELAXED, __HIP_MEMORY_SCOPE_SYSTEM);
}
__device__ __forceinline__ void cstore(float* p, float v) {
    __hip_atomic_store(p, v, __ATOMIC_RELAXED, __HIP_MEMORY_SCOPE_SYSTEM);
}

// ---------------- ELL build + barrier-counter zeroing ---------------------
__global__ __launch_bounds__(256) void build_ell(const float* __restrict__ gso,
                                                 int* __restrict__ ellc,
                                                 float* __restrict__ ellv,
                                                 int* __restrict__ rcnt,
                                                 unsigned* __restrict__ bar) {
    int gtid = blockIdx.x * 256 + threadIdx.x;
    if (gtid < BARSZ) bar[gtid] = 0u;
    int row  = gtid >> 6;
    int lane = threadIdx.x & 63;
    if (row >= NV) return;
    const float* r = gso + (size_t)row * NV;
    int cnt = 0;
    const int base = row * CAP;
    for (int c0 = 0; c0 < NV; c0 += 256) {
        const float4 v = *reinterpret_cast<const float4*>(r + c0 + lane * 4);
        const float vv[4] = {v.x, v.y, v.z, v.w};
#pragma unroll
        for (int q = 0; q < 4; ++q) {
            unsigned long long m = __ballot(vv[q] != 0.0f);
            if (vv[q] != 0.0f) {
                int pos = cnt + __popcll(m & ((1ull << lane) - 1ull));
                if (pos < CAP) {
                    ellc[base + pos] = c0 + lane * 4 + q;
                    ellv[base + pos] = vv[q];
                }
            }
            cnt += __popcll(m);
        }
    }
    if (lane == 0) rcnt[row] = cnt < CAP ? cnt : CAP;
}

struct Params {
    const int*   ellc; const float* ellv; const int* rcnt;
    const float* x;
    const float *eWr, *ebr, *eWu, *ebu, *eWc, *ebc;
    const float *dWr, *dbr, *dWu, *dbu, *dWc, *dbc;
    const float *W1, *b1, *W2, *b2;
    float *XHh, *XHx, *X1h, *X1x, *XCh, *XCx, *Y1h, *Y1x;
    unsigned* bar;
    float* out;
};

__global__ __launch_bounds__(BLK, 2) void dcrnn_persist(Params P) {
    const int lane = threadIdx.x & 63;
    const int j    = lane & 31;
    const int b    = lane >> 5;
    const int jb   = b << 5;
    const int wav  = blockIdx.x * WPB + (threadIdx.x >> 6);
    int barRound = 0;

    auto BAR = [&]() {
        ++barRound;
        // __syncthreads drains each wave's vmcnt before s_barrier: all
        // sc0sc1 stores are at the coherent point before thread0 arrives.
        asm volatile("s_waitcnt vmcnt(0)" ::: "memory");
        __syncthreads();
        if (threadIdx.x == 0) {
            const unsigned g = (unsigned)blockIdx.x / BPG;
            unsigned old = __hip_atomic_fetch_add(&P.bar[32 + g * 32], 1u,
                               __ATOMIC_RELAXED, __HIP_MEMORY_SCOPE_SYSTEM);
            if (old == (unsigned)(barRound * BPG) - 1u)
                __hip_atomic_fetch_add(&P.bar[0], 1u,
                    __ATOMIC_RELAXED, __HIP_MEMORY_SCOPE_SYSTEM);
            while (__hip_atomic_load(&P.bar[0], __ATOMIC_RELAXED,
                                     __HIP_MEMORY_SCOPE_SYSTEM)
                   < (unsigned)(barRound * NGROUPS))
                __builtin_amdgcn_s_sleep(2);
        }
        __syncthreads();
    };

    // ---- persistent per-wave state (4 nodes each) ----
    int   nn[NPW];  int col[NPW]; float val[NPW];
    float h[NPW], u[NPW], xx[NPW], xch[NPW];
    float x1h[NPW], x1x[NPW], y1h[NPW], y1x[NPW];
    int kmax = 0;
#pragma unroll
    for (int i = 0; i < NPW; ++i) {
        nn[i] = wav + i * NWAVES;
        const int cnt = P.rcnt[nn[i]];
        kmax = cnt > kmax ? cnt : kmax;
        col[i] = lane < cnt ? P.ellc[nn[i] * CAP + lane] : 0;
        val[i] = lane < cnt ? P.ellv[nn[i] * CAP + lane] : 0.f;
        h[i]  = 0.f;
        xx[i] = P.x[((size_t)b * TT) * NV + nn[i]];
        cstore(&P.XHh[nn[i] * 64 + lane], 0.f);
        if (j == 0) cstore(&P.XHx[nn[i] * 2 + b], xx[i]);
    }
    const int kmaxE = (kmax + 1) & ~1;   // pad-safe: val=0 beyond cnt

    auto GATHER = [&](const float* __restrict__ Xh, const float* __restrict__ Xx,
                      float (&ah)[NPW], float (&ax)[NPW]) {
#pragma unroll
        for (int i = 0; i < NPW; ++i) { ah[i] = 0.f; ax[i] = 0.f; }
        for (int k = 0; k < kmaxE; k += 2) {
#pragma unroll
            for (int kk = 0; kk < 2; ++kk) {
#pragma unroll
                for (int i = 0; i < NPW; ++i) {
                    const int   c = __shfl(col[i], k + kk);
                    const float v = __shfl(val[i], k + kk);
                    ah[i] = fmaf(v, cload(&Xh[c * 64 + lane]), ah[i]);
                    ax[i] = fmaf(v, cload(&Xx[c * 2 + b]),     ax[i]);
                }
            }
        }
    };

    BAR();

    for (int cell = 0; cell < 2 * TT; ++cell) {
        const bool enc = cell < TT;
        const float* Wr = enc ? P.eWr : P.dWr;
        const float* br = enc ? P.ebr : P.dbr;
        const float* Wu = enc ? P.eWu : P.dWu;
        const float* bu = enc ? P.ebu : P.dbu;
        const float* Wc = enc ? P.eWc : P.dWc;
        const float* bc = enc ? P.ebc : P.dbc;
        const int mode = enc ? ((cell + 1 < TT) ? 0 : 1) : 2;

        // ---- S1: X1 = S @ XH ----
        GATHER(P.XHh, P.XHx, x1h, x1x);
#pragma unroll
        for (int i = 0; i < NPW; ++i) {
            cstore(&P.X1h[nn[i] * 64 + lane], x1h[i]);
            if (j == 0) cstore(&P.X1x[nn[i] * 2 + b], x1x[i]);
        }
        BAR();

        // ---- S2: X2 = S @ X1; r,u gates; XC = [x, r*h] ----
        {
            float x2h[NPW], x2x[NPW];
            GATHER(P.X1h, P.X1x, x2h, x2x);
            float accr[NPW], accu[NPW];
            const float brj = br[j], buj = bu[j];
#pragma unroll
            for (int i = 0; i < NPW; ++i) {
                accr[i] = fmaf(xx[i],  Wr[j],           brj);
                accr[i] = fmaf(x1x[i], Wr[33 * 32 + j], accr[i]);
                accr[i] = fmaf(x2x[i], Wr[66 * 32 + j], accr[i]);
                accu[i] = fmaf(xx[i],  Wu[j],           buj);
                accu[i] = fmaf(x1x[i], Wu[33 * 32 + j], accu[i]);
                accu[i] = fmaf(x2x[i], Wu[66 * 32 + j], accu[i]);
            }
#pragma unroll
            for (int m = 0; m < 32; ++m) {
                const float wr0 = Wr[(1 + m) * 32 + j],  wu0 = Wu[(1 + m) * 32 + j];
                const float wr1 = Wr[(34 + m) * 32 + j], wu1 = Wu[(34 + m) * 32 + j];
                const float wr2 = Wr[(67 + m) * 32 + j], wu2 = Wu[(67 + m) * 32 + j];
#pragma unroll
                for (int i = 0; i < NPW; ++i) {
                    const float f0 = __shfl(h[i],   jb + m);
                    const float f1 = __shfl(x1h[i], jb + m);
                    const float f2 = __shfl(x2h[i], jb + m);
                    accr[i] = fmaf(f0, wr0, accr[i]); accu[i] = fmaf(f0, wu0, accu[i]);
                    accr[i] = fmaf(f1, wr1, accr[i]); accu[i] = fmaf(f1, wu1, accu[i]);
                    accr[i] = fmaf(f2, wr2, accr[i]); accu[i] = fmaf(f2, wu2, accu[i]);
                }
            }
#pragma unroll
            for (int i = 0; i < NPW; ++i) {
                const float rg = 1.f / (1.f + expf(-accr[i]));
                u[i]   = 1.f / (1.f + expf(-accu[i]));
                xch[i] = rg * h[i];
                cstore(&P.XCh[nn[i] * 64 + lane], xch[i]);
                if (j == 0) cstore(&P.XCx[nn[i] * 2 + b], xx[i]);
            }
        }
        BAR();

        // ---- S3: Y1 = S @ XC ----
        GATHER(P.XCh, P.XCx, y1h, y1x);
#pragma unroll
        for (int i = 0; i < NPW; ++i) {
            cstore(&P.Y1h[nn[i] * 64 + lane], y1h[i]);
            if (j == 0) cstore(&P.Y1x[nn[i] * 2 + b], y1x[i]);
        }
        BAR();

        // ---- S4: Y2 = S @ Y1; c = tanh; h = u*h+(1-u)*c; next x ----
        {
            float y2h[NPW], y2x[NPW];
            GATHER(P.Y1h, P.Y1x, y2h, y2x);
            float acc[NPW];
            const float bcj = bc[j];
#pragma unroll
            for (int i = 0; i < NPW; ++i) {
                acc[i] = fmaf(xx[i],  Wc[j],           bcj);
                acc[i] = fmaf(y1x[i], Wc[33 * 32 + j], acc[i]);
                acc[i] = fmaf(y2x[i], Wc[66 * 32 + j], acc[i]);
            }
#pragma unroll
            for (int m = 0; m < 32; ++m) {
                const float wc0 = Wc[(1 + m) * 32 + j];
                const float wc1 = Wc[(34 + m) * 32 + j];
                const float wc2 = Wc[(67 + m) * 32 + j];
#pragma unroll
                for (int i = 0; i < NPW; ++i) {
                    acc[i] = fmaf(__shfl(xch[i], jb + m), wc0, acc[i]);
                    acc[i] = fmaf(__shfl(y1h[i], jb + m), wc1, acc[i]);
                    acc[i] = fmaf(__shfl(y2h[i], jb + m), wc2, acc[i]);
                }
            }
#pragma unroll
            for (int i = 0; i < NPW; ++i) {
                const float cc = tanhf(acc[i]);
                h[i] = u[i] * h[i] + (1.f - u[i]) * cc;
                cstore(&P.XHh[nn[i] * 64 + lane], h[i]);
            }
            if (mode == 2) {
                // decoder head: z = relu(h@W1+b1); pred = z@W2+b2
                float z[NPW];
                const float b1j = P.b1[j];
#pragma unroll
                for (int i = 0; i < NPW; ++i) z[i] = b1j;
#pragma unroll
                for (int m = 0; m < 32; ++m) {
                    const float w = P.W1[m * 32 + j];
#pragma unroll
                    for (int i = 0; i < NPW; ++i)
                        z[i] = fmaf(__shfl(h[i], jb + m), w, z[i]);
                }
                const float w2j = P.W2[j];
#pragma unroll
                for (int i = 0; i < NPW; ++i) {
                    float pz = fmaxf(z[i], 0.f) * w2j;
#pragma unroll
                    for (int off = 16; off; off >>= 1) pz += __shfl_xor(pz, off);
                    const float pred = pz + P.b2[0];
                    xx[i] = pred;
                    if (j == 0) {
                        P.out[((size_t)b * TT + (cell - TT)) * NV + nn[i]] = pred;
                        cstore(&P.XHx[nn[i] * 2 + b], pred);
                    }
                }
            } else {
#pragma unroll
                for (int i = 0; i < NPW; ++i) {
                    xx[i] = (mode == 0)
                        ? P.x[((size_t)b * TT + (cell + 1)) * NV + nn[i]] : 0.f;
                    if (j == 0) cstore(&P.XHx[nn[i] * 2 + b], xx[i]);
                }
            }
        }
        BAR();
    }
}

extern "C" void kernel_launch(void* const* d_in, const int* in_sizes, int n_in,
                              void* d_out, int out_size, void* d_ws, size_t ws_size,
                              hipStream_t stream) {
    const float* x   = (const float*)d_in[0];
    // d_in[1] = edge_index (gso already encodes it)
    const float* gso = (const float*)d_in[2];

    char* p = (char*)d_ws;
    auto alloc = [&](size_t bytes) {
        char* q = p;
        p += (bytes + 255) & ~(size_t)255;
        return q;
    };
    int*      ellc = (int*)     alloc((size_t)NV * CAP * 4);
    float*    ellv = (float*)   alloc((size_t)NV * CAP * 4);
    int*      rcnt = (int*)     alloc((size_t)NV * 4);
    unsigned* bar  = (unsigned*)alloc(BARSZ * 4);
    float*    XHh  = (float*)   alloc((size_t)NV * 64 * 4);
    float*    XHx  = (float*)   alloc((size_t)NV * 2 * 4);
    float*    X1h  = (float*)   alloc((size_t)NV * 64 * 4);
    float*    X1x  = (float*)   alloc((size_t)NV * 2 * 4);
    float*    XCh  = (float*)   alloc((size_t)NV * 64 * 4);
    float*    XCx  = (float*)   alloc((size_t)NV * 2 * 4);
    float*    Y1h  = (float*)   alloc((size_t)NV * 64 * 4);
    float*    Y1x  = (float*)   alloc((size_t)NV * 2 * 4);

    hipLaunchKernelGGL(build_ell, dim3(NV / 4), dim3(256), 0, stream,
                       gso, ellc, ellv, rcnt, bar);

    Params P;
    P.ellc = ellc; P.ellv = ellv; P.rcnt = rcnt;
    P.x = x;
    P.eWr = (const float*)d_in[3];  P.ebr = (const float*)d_in[4];
    P.eWu = (const float*)d_in[5];  P.ebu = (const float*)d_in[6];
    P.eWc = (const float*)d_in[7];  P.ebc = (const float*)d_in[8];
    P.dWr = (const float*)d_in[9];  P.dbr = (const float*)d_in[10];
    P.dWu = (const float*)d_in[11]; P.dbu = (const float*)d_in[12];
    P.dWc = (const float*)d_in[13]; P.dbc = (const float*)d_in[14];
    P.W1  = (const float*)d_in[15]; P.b1  = (const float*)d_in[16];
    P.W2  = (const float*)d_in[17]; P.b2  = (const float*)d_in[18];
    P.XHh = XHh; P.XHx = XHx; P.X1h = X1h; P.X1x = X1x;
    P.XCh = XCh; P.XCx = XCx; P.Y1h = Y1h; P.Y1x = Y1x;
    P.bar = bar;
    P.out = (float*)d_out;

    hipLaunchKernelGGL(dcrnn_persist, dim3(GRD), dim3(BLK), 0, stream, P);
}

// Round 9
// 12971.413 us; speedup vs baseline: 1.9357x; 1.9357x over previous
//
#include <hip/hip_runtime.h>

// DCRNN encoder-decoder on MI355X (gfx950).
// gso (8192^2 dense fp32) is ~0.2% dense (~17 nnz/row, zeros exact): ELL once.
// Sync-cost ladder measured: kernel boundary ~32us (R2) < agent barrier 106us
// (R5, per-block wbl2+inv nukes L2) < uncached-data barrier ~128us (R8, sc0sc1
// loads deny the 17x row reuse -> 34.9 GB fabric traffic, BW-bound).
// => Multi-launch with HALVED dependency points: 2 kernels/cell. Hop-2 is
// computed by recomputing hop-1 on the fly for each neighbor (289 L2-resident
// row reads, identical FMA association order as reference S@(S@X)).
// Layout: wave-per-node; features Xh[n][64] (lane = b*32+j) = 256B coalesced
// rows; Xx[n][2] x-scalars. Gates/update/head fused in-wave via __shfl.

#define NV  8192
#define TT  24
#define CAP 64          // ELL capacity (row degree ~Poisson(17); P(>=64)~0)
#define HD  32

// ---------------- ELL build (one wave/row, float4+ballot) + XH init -------
__global__ __launch_bounds__(256) void build_ell(const float* __restrict__ gso,
                                                 int* __restrict__ ellc,
                                                 float* __restrict__ ellv,
                                                 int* __restrict__ rcnt,
                                                 float* __restrict__ XHh,
                                                 float* __restrict__ XHx,
                                                 const float* __restrict__ x) {
    int gtid = blockIdx.x * 256 + threadIdx.x;
    int row  = gtid >> 6;
    int lane = threadIdx.x & 63;
    if (row >= NV) return;
    const float* r = gso + (size_t)row * NV;
    int cnt = 0;
    const int base = row * CAP;
    for (int c0 = 0; c0 < NV; c0 += 256) {
        const float4 v = *reinterpret_cast<const float4*>(r + c0 + lane * 4);
        const float vv[4] = {v.x, v.y, v.z, v.w};
#pragma unroll
        for (int q = 0; q < 4; ++q) {
            unsigned long long m = __ballot(vv[q] != 0.0f);
            if (vv[q] != 0.0f) {
                int pos = cnt + __popcll(m & ((1ull << lane) - 1ull));
                if (pos < CAP) {
                    ellc[base + pos] = c0 + lane * 4 + q;
                    ellv[base + pos] = vv[q];
                }
            }
            cnt += __popcll(m);
        }
    }
    if (lane == 0) rcnt[row] = cnt < CAP ? cnt : CAP;
    XHh[row * 64 + lane] = 0.f;                               // h0 = 0
    if (lane < 2) XHx[row * 2 + lane] = x[((size_t)lane * TT) * NV + row];
}

// ---- fused 2-hop gather: a = (S@(S@F))[n], a1 = (S@F)[n] via self-loop ----
// Identical association order to reference: x1[m] = sum_p S[m,p] F[p] (ELL
// order), then x2[n] = sum_m S[n,m] x1[m]. Self-loop S[n,n]>0 always exists
// (A += I), so x1[n] is captured when ck == n.
#define GATHER2(Fh, Fx, x1, x1x, x2, x2x)                                   \
    float x1 = 0.f, x1x = 0.f, x2 = 0.f, x2x = 0.f;                         \
    for (int k = 0; k < cnt; ++k) {                                         \
        const int   ck = __shfl(myc, k);                                    \
        const float vk = __shfl(myv, k);                                    \
        const int   pc = __shfl(nbc, k);                                    \
        const int   nc = lane < pc ? ellc[ck * CAP + lane] : 0;             \
        const float nv = lane < pc ? ellv[ck * CAP + lane] : 0.f;           \
        float a = 0.f, ax = 0.f;                                            \
        for (int p = 0; p < pc; ++p) {                                      \
            const int   c = __shfl(nc, p);                                  \
            const float v = __shfl(nv, p);                                  \
            a  = fmaf(v, Fh[c * 64 + lane], a);                             \
            ax = fmaf(v, Fx[c * 2 + b], ax);                                \
        }                                                                   \
        x2 = fmaf(vk, a, x2); x2x = fmaf(vk, ax, x2x);                      \
        if (ck == n) { x1 = a; x1x = ax; }                                  \
    }

// -------- kernel A: r,u gates from 2-hop gconv of XH; XC = [x, r*h] -------
__global__ __launch_bounds__(512) void gates_k(const int* __restrict__ ellc,
                                               const float* __restrict__ ellv,
                                               const int* __restrict__ rcnt,
                                               const float* __restrict__ XHh,
                                               const float* __restrict__ XHx,
                                               const float* __restrict__ Wr,
                                               const float* __restrict__ br,
                                               const float* __restrict__ Wu,
                                               const float* __restrict__ bu,
                                               float* __restrict__ U,
                                               float* __restrict__ XCh,
                                               float* __restrict__ XCx) {
    const int lane = threadIdx.x & 63;
    const int j = lane & 31, b = lane >> 5, jb = b << 5;
    const int n = blockIdx.x * 8 + (threadIdx.x >> 6);
    const int   cnt = rcnt[n];
    const int   myc = lane < cnt ? ellc[n * CAP + lane] : 0;
    const float myv = lane < cnt ? ellv[n * CAP + lane] : 0.f;
    const int   nbc = lane < cnt ? rcnt[myc] : 0;
    GATHER2(XHh, XHx, x1, x1x, x2, x2x)
    const float h  = XHh[n * 64 + lane];
    const float xh = XHx[n * 2 + b];
    float accr = br[j], accu = bu[j];
    accr = fmaf(xh,  Wr[j],           accr);  accu = fmaf(xh,  Wu[j],           accu);
    accr = fmaf(x1x, Wr[33 * 32 + j], accr);  accu = fmaf(x1x, Wu[33 * 32 + j], accu);
    accr = fmaf(x2x, Wr[66 * 32 + j], accr);  accu = fmaf(x2x, Wu[66 * 32 + j], accu);
#pragma unroll
    for (int m = 0; m < 32; ++m) {
        const float f0 = __shfl(h,  jb + m);
        const float f1 = __shfl(x1, jb + m);
        const float f2 = __shfl(x2, jb + m);
        accr = fmaf(f0, Wr[(1 + m) * 32 + j],  accr);
        accu = fmaf(f0, Wu[(1 + m) * 32 + j],  accu);
        accr = fmaf(f1, Wr[(34 + m) * 32 + j], accr);
        accu = fmaf(f1, Wu[(34 + m) * 32 + j], accu);
        accr = fmaf(f2, Wr[(67 + m) * 32 + j], accr);
        accu = fmaf(f2, Wu[(67 + m) * 32 + j], accu);
    }
    const float rg = 1.f / (1.f + expf(-accr));
    const float ug = 1.f / (1.f + expf(-accu));
    U[n * 64 + lane]   = ug;
    XCh[n * 64 + lane] = rg * h;
    if (j == 0) XCx[n * 2 + b] = xh;
}

// -------- kernel B: candidate from 2-hop gconv of XC; h update; head ------
// mode 0: next xin = x[t_next]; 1: zero; 2: decoder head -> out + next xin
__global__ __launch_bounds__(512) void cand_k(const int* __restrict__ ellc,
                                              const float* __restrict__ ellv,
                                              const int* __restrict__ rcnt,
                                              const float* __restrict__ XCh,
                                              const float* __restrict__ XCx,
                                              float* XHh, float* XHx,
                                              const float* __restrict__ U,
                                              const float* __restrict__ Wc,
                                              const float* __restrict__ bc,
                                              const float* __restrict__ x,
                                              const float* __restrict__ W1,
                                              const float* __restrict__ b1,
                                              const float* __restrict__ W2,
                                              const float* __restrict__ b2,
                                              float* __restrict__ out,
                                              int mode, int t_next, int t_out) {
    const int lane = threadIdx.x & 63;
    const int j = lane & 31, b = lane >> 5, jb = b << 5;
    const int n = blockIdx.x * 8 + (threadIdx.x >> 6);
    const int   cnt = rcnt[n];
    const int   myc = lane < cnt ? ellc[n * CAP + lane] : 0;
    const float myv = lane < cnt ? ellv[n * CAP + lane] : 0.f;
    const int   nbc = lane < cnt ? rcnt[myc] : 0;
    GATHER2(XCh, XCx, y1, y1x, y2, y2x)
    const float h   = XHh[n * 64 + lane];     // own row only (in-place safe)
    const float xc  = XCx[n * 2 + b];
    const float xch = XCh[n * 64 + lane];     // r*h own row
    float acc = bc[j];
    acc = fmaf(xc,  Wc[j],           acc);
    acc = fmaf(y1x, Wc[33 * 32 + j], acc);
    acc = fmaf(y2x, Wc[66 * 32 + j], acc);
#pragma unroll
    for (int m = 0; m < 32; ++m) {
        acc = fmaf(__shfl(xch, jb + m), Wc[(1 + m) * 32 + j],  acc);
        acc = fmaf(__shfl(y1,  jb + m), Wc[(34 + m) * 32 + j], acc);
        acc = fmaf(__shfl(y2,  jb + m), Wc[(67 + m) * 32 + j], acc);
    }
    const float cc = tanhf(acc);
    const float u  = U[n * 64 + lane];
    const float hn = u * h + (1.f - u) * cc;
    XHh[n * 64 + lane] = hn;
    if (mode == 2) {
        // z = relu(hn @ W1 + b1); pred = z @ W2 + b2
        float z = b1[j];
#pragma unroll
        for (int m = 0; m < 32; ++m)
            z = fmaf(__shfl(hn, jb + m), W1[m * 32 + j], z);
        float pz = fmaxf(z, 0.f) * W2[j];
#pragma unroll
        for (int off = 16; off; off >>= 1) pz += __shfl_xor(pz, off);
        if (j == 0) {
            const float pred = pz + b2[0];
            out[((size_t)b * TT + t_out) * NV + n] = pred;
            XHx[n * 2 + b] = pred;
        }
    } else if (j == 0) {
        XHx[n * 2 + b] = (mode == 0)
            ? x[((size_t)b * TT + t_next) * NV + n] : 0.f;
    }
}

extern "C" void kernel_launch(void* const* d_in, const int* in_sizes, int n_in,
                              void* d_out, int out_size, void* d_ws, size_t ws_size,
                              hipStream_t stream) {
    const float* x      = (const float*)d_in[0];
    // d_in[1] = edge_index (gso already encodes it)
    const float* gso    = (const float*)d_in[2];
    const float* enc_Wr = (const float*)d_in[3];
    const float* enc_br = (const float*)d_in[4];
    const float* enc_Wu = (const float*)d_in[5];
    const float* enc_bu = (const float*)d_in[6];
    const float* enc_Wc = (const float*)d_in[7];
    const float* enc_bc = (const float*)d_in[8];
    const float* dec_Wr = (const float*)d_in[9];
    const float* dec_br = (const float*)d_in[10];
    const float* dec_Wu = (const float*)d_in[11];
    const float* dec_bu = (const float*)d_in[12];
    const float* dec_Wc = (const float*)d_in[13];
    const float* dec_bc = (const float*)d_in[14];
    const float* po_W1  = (const float*)d_in[15];
    const float* po_b1  = (const float*)d_in[16];
    const float* po_W2  = (const float*)d_in[17];
    const float* po_b2  = (const float*)d_in[18];
    float* out = (float*)d_out;

    char* p = (char*)d_ws;
    auto alloc = [&](size_t bytes) {
        char* q = p;
        p += (bytes + 255) & ~(size_t)255;
        return q;
    };
    int*   ellc = (int*)  alloc((size_t)NV * CAP * 4);
    float* ellv = (float*)alloc((size_t)NV * CAP * 4);
    int*   rcnt = (int*)  alloc((size_t)NV * 4);
    float* XHh  = (float*)alloc((size_t)NV * 64 * 4);
    float* XHx  = (float*)alloc((size_t)NV * 2 * 4);
    float* XCh  = (float*)alloc((size_t)NV * 64 * 4);
    float* XCx  = (float*)alloc((size_t)NV * 2 * 4);
    float* U    = (float*)alloc((size_t)NV * 64 * 4);

    const dim3 blk(512);
    const dim3 g_node(NV / 8);    // 1 wave per node, 8 waves/block

    hipLaunchKernelGGL(build_ell, dim3(NV / 4), dim3(256), 0, stream,
                       gso, ellc, ellv, rcnt, XHh, XHx, x);

    // encoder: 24 cells x 2 kernels
    for (int t = 0; t < TT; ++t) {
        hipLaunchKernelGGL(gates_k, g_node, blk, 0, stream,
                           ellc, ellv, rcnt, XHh, XHx,
                           enc_Wr, enc_br, enc_Wu, enc_bu, U, XCh, XCx);
        hipLaunchKernelGGL(cand_k, g_node, blk, 0, stream,
                           ellc, ellv, rcnt, XCh, XCx, XHh, XHx, U,
                           enc_Wc, enc_bc, x, po_W1, po_b1, po_W2, po_b2,
                           out, (t + 1 < TT) ? 0 : 1, t + 1, 0);
    }
    // decoder: 24 cells x 2 kernels (head fused into cand_k)
    for (int t = 0; t < TT; ++t) {
        hipLaunchKernelGGL(gates_k, g_node, blk, 0, stream,
                           ellc, ellv, rcnt, XHh, XHx,
                           dec_Wr, dec_br, dec_Wu, dec_bu, U, XCh, XCx);
        hipLaunchKernelGGL(cand_k, g_node, blk, 0, stream,
                           ellc, ellv, rcnt, XCh, XCx, XHh, XHx, U,
                           dec_Wc, dec_bc, x, po_W1, po_b1, po_W2, po_b2,
                           out, 2, 0, t);
    }
}

// Round 12
// 12211.152 us; speedup vs baseline: 2.0562x; 1.0623x over previous
//
#include <hip/hip_runtime.h>

// DCRNN encoder-decoder on MI355X (gfx950).
// gso (8192^2 dense fp32) is ~0.2% dense (~17 nnz/row, zeros exact).
// Sync ladder measured: kernel boundary ~32us (R2) < agent barrier 106us (R5)
// < uncached-data barrier ~128us (R8). R9 (nested 2-hop recompute, 97
// dispatches) = 12.9ms: GATHER2's k-loop serialized ~17 x 400cy ELL-row
// stalls -> 130us/kernel, VALUBusy 10%.
// R10-R12: PRECOMPUTE flat S2 = S@S as ELL (~306 entries/node, duplicate
// cols kept -> exact reassociation of the reference double sum). Hot kernels
// do flat independent 256B row gathers (readlane broadcast, one wait per 64
// entries; all load addresses register-derived, no dependent-load chains).
// 2 kernels/cell, 98 dispatches total.

#define NV  8192
#define TT  24
#define CAP 64          // ELL capacity (row degree ~Poisson(17); P(>=64)~0)

// ---------------- ELL build (one wave/row, float4+ballot) + XH init -------
__global__ __launch_bounds__(256) void build_ell(const float* __restrict__ gso,
                                                 int* __restrict__ ellc,
                                                 float* __restrict__ ellv,
                                                 int* __restrict__ rcnt,
                                                 float* __restrict__ XHh,
                                                 float* __restrict__ XHx,
                                                 const float* __restrict__ x) {
    int gtid = blockIdx.x * 256 + threadIdx.x;
    int row  = gtid >> 6;
    int lane = threadIdx.x & 63;
    if (row >= NV) return;
    const float* r = gso + (size_t)row * NV;
    int cnt = 0;
    const int base = row * CAP;
    for (int c0 = 0; c0 < NV; c0 += 256) {
        const float4 v = *reinterpret_cast<const float4*>(r + c0 + lane * 4);
        const float vv[4] = {v.x, v.y, v.z, v.w};
#pragma unroll
        for (int q = 0; q < 4; ++q) {
            unsigned long long m = __ballot(vv[q] != 0.0f);
            if (vv[q] != 0.0f) {
                int pos = cnt + __popcll(m & ((1ull << lane) - 1ull));
                if (pos < CAP) {
                    ellc[base + pos] = c0 + lane * 4 + q;
                    ellv[base + pos] = vv[q];
                }
            }
            cnt += __popcll(m);
        }
    }
    if (lane == 0) rcnt[row] = cnt < CAP ? cnt : CAP;
    XHh[row * 64 + lane] = 0.f;                               // h0 = 0
    if (lane < 2) XHx[row * 2 + lane] = x[((size_t)lane * TT) * NV + row];
}

// --------- S2 = S@S as flat ELL: entries (col[m][p], S[n,m]*S[m][p]) ------
__global__ __launch_bounds__(512) void build_s2(const int* __restrict__ ellc,
                                                const float* __restrict__ ellv,
                                                const int* __restrict__ rcnt,
                                                int* __restrict__ ell2c,
                                                float* __restrict__ ell2v,
                                                int* __restrict__ rcnt2,
                                                int cap2) {
    const int lane = threadIdx.x & 63;
    const int n = blockIdx.x * 8 + (threadIdx.x >> 6);
    const int cnt = rcnt[n];
    const int   c = lane < cnt ? ellc[n * CAP + lane] : 0;
    const float v = lane < cnt ? ellv[n * CAP + lane] : 0.f;
    const int  nb = lane < cnt ? rcnt[c] : 0;
    // exclusive prefix sum of nb across 64 lanes
    int off = nb;
#pragma unroll
    for (int d = 1; d < 64; d <<= 1) {
        int t = __shfl_up(off, d);
        if (lane >= d) off += t;
    }
    off -= nb;
    const int total = __shfl(off + nb, 63);
    const size_t base2 = (size_t)n * cap2;
    for (int k = 0; k < cnt; ++k) {
        const int   ck   = __shfl(c, k);
        const float vk   = __shfl(v, k);
        const int   offk = __shfl(off, k);
        const int   pc   = __shfl(nb, k);
        if (lane < pc) {
            const int idx = offk + lane;
            if (idx < cap2) {
                ell2c[base2 + idx] = ellc[ck * CAP + lane];
                ell2v[base2 + idx] = vk * ellv[ck * CAP + lane];
            }
        }
    }
    if (lane == 0) rcnt2[n] = total < cap2 ? total : cap2;
}

// ---- flat 2-tap gather: x1 = (S@F)[n], x2 = (S2@F)[n]; 256B row loads ----
#define GATHER12(Fh, Fx, x1, x1x, x2, x2x)                                  \
    float x1 = 0.f, x1x = 0.f, x2 = 0.f, x2x = 0.f;                         \
    {                                                                       \
        const int   cnt = rcnt[n];                                          \
        const int   c1  = lane < cnt ? ellc[n * CAP + lane] : 0;            \
        const float v1  = lane < cnt ? ellv[n * CAP + lane] : 0.f;          \
        for (int k = 0; k < cnt; ++k) {                                     \
            const int   cc = __shfl(c1, k);                                 \
            const float vv = __shfl(v1, k);                                 \
            x1  = fmaf(vv, Fh[cc * 64 + lane], x1);                         \
            x1x = fmaf(vv, Fx[cc * 2 + b], x1x);                            \
        }                                                                   \
        const int t2 = rcnt2[n];                                            \
        const size_t base2 = (size_t)n * cap2;                              \
        for (int g = 0; g < t2; g += 64) {                                  \
            const int e = g + lane;                                         \
            const int   c2  = e < t2 ? ell2c[base2 + e] : 0;                \
            const float vv2 = e < t2 ? ell2v[base2 + e] : 0.f;              \
            const int lim = (t2 - g) < 64 ? (t2 - g) : 64;                  \
            _Pragma("unroll 8")                                             \
            for (int q = 0; q < lim; ++q) {                                 \
                const int   cc = __shfl(c2, q);                             \
                const float vv = __shfl(vv2, q);                            \
                x2  = fmaf(vv, Fh[cc * 64 + lane], x2);                     \
                x2x = fmaf(vv, Fx[cc * 2 + b], x2x);                        \
            }                                                               \
        }                                                                   \
    }

// -------- kernel A: r,u gates from 2-hop gconv of XH; XC = [x, r*h] -------
__global__ __launch_bounds__(512) void gates_k(const int* __restrict__ ellc,
                                               const float* __restrict__ ellv,
                                               const int* __restrict__ rcnt,
                                               const int* __restrict__ ell2c,
                                               const float* __restrict__ ell2v,
                                               const int* __restrict__ rcnt2,
                                               int cap2,
                                               const float* __restrict__ XHh,
                                               const float* __restrict__ XHx,
                                               const float* __restrict__ Wr,
                                               const float* __restrict__ br,
                                               const float* __restrict__ Wu,
                                               const float* __restrict__ bu,
                                               float* __restrict__ U,
                                               float* __restrict__ XCh,
                                               float* __restrict__ XCx) {
    const int lane = threadIdx.x & 63;
    const int j = lane & 31, b = lane >> 5, jb = b << 5;
    const int n = blockIdx.x * 8 + (threadIdx.x >> 6);
    GATHER12(XHh, XHx, x1, x1x, x2, x2x)
    const float h  = XHh[n * 64 + lane];
    const float xh = XHx[n * 2 + b];
    float accr = br[j], accu = bu[j];
    accr = fmaf(xh,  Wr[j],           accr);  accu = fmaf(xh,  Wu[j],           accu);
    accr = fmaf(x1x, Wr[33 * 32 + j], accr);  accu = fmaf(x1x, Wu[33 * 32 + j], accu);
    accr = fmaf(x2x, Wr[66 * 32 + j], accr);  accu = fmaf(x2x, Wu[66 * 32 + j], accu);
#pragma unroll
    for (int m = 0; m < 32; ++m) {
        const float f0 = __shfl(h,  jb + m);
        const float f1 = __shfl(x1, jb + m);
        const float f2 = __shfl(x2, jb + m);
        accr = fmaf(f0, Wr[(1 + m) * 32 + j],  accr);
        accu = fmaf(f0, Wu[(1 + m) * 32 + j],  accu);
        accr = fmaf(f1, Wr[(34 + m) * 32 + j], accr);
        accu = fmaf(f1, Wu[(34 + m) * 32 + j], accu);
        accr = fmaf(f2, Wr[(67 + m) * 32 + j], accr);
        accu = fmaf(f2, Wu[(67 + m) * 32 + j], accu);
    }
    const float rg = 1.f / (1.f + expf(-accr));
    const float ug = 1.f / (1.f + expf(-accu));
    U[n * 64 + lane]   = ug;
    XCh[n * 64 + lane] = rg * h;
    if (j == 0) XCx[n * 2 + b] = xh;
}

// -------- kernel B: candidate from 2-hop gconv of XC; h update; head ------
// mode 0: next xin = x[t_next]; 1: zero; 2: decoder head -> out + next xin
__global__ __launch_bounds__(512) void cand_k(const int* __restrict__ ellc,
                                              const float* __restrict__ ellv,
                                              const int* __restrict__ rcnt,
                                              const int* __restrict__ ell2c,
                                              const float* __restrict__ ell2v,
                                              const int* __restrict__ rcnt2,
                                              int cap2,
                                              const float* __restrict__ XCh,
                                              const float* __restrict__ XCx,
                                              float* XHh, float* XHx,
                                              const float* __restrict__ U,
                                              const float* __restrict__ Wc,
                                              const float* __restrict__ bc,
                                              const float* __restrict__ x,
                                              const float* __restrict__ W1,
                                              const float* __restrict__ b1,
                                              const float* __restrict__ W2,
                                              const float* __restrict__ b2,
                                              float* __restrict__ out,
                                              int mode, int t_next, int t_out) {
    const int lane = threadIdx.x & 63;
    const int j = lane & 31, b = lane >> 5, jb = b << 5;
    const int n = blockIdx.x * 8 + (threadIdx.x >> 6);
    GATHER12(XCh, XCx, y1, y1x, y2, y2x)
    const float h   = XHh[n * 64 + lane];     // own row only (in-place safe)
    const float xc  = XCx[n * 2 + b];
    const float xch = XCh[n * 64 + lane];     // r*h own row
    float acc = bc[j];
    acc = fmaf(xc,  Wc[j],           acc);
    acc = fmaf(y1x, Wc[33 * 32 + j], acc);
    acc = fmaf(y2x, Wc[66 * 32 + j], acc);
#pragma unroll
    for (int m = 0; m < 32; ++m) {
        acc = fmaf(__shfl(xch, jb + m), Wc[(1 + m) * 32 + j],  acc);
        acc = fmaf(__shfl(y1,  jb + m), Wc[(34 + m) * 32 + j], acc);
        acc = fmaf(__shfl(y2,  jb + m), Wc[(67 + m) * 32 + j], acc);
    }
    const float cc = tanhf(acc);
    const float u  = U[n * 64 + lane];
    const float hn = u * h + (1.f - u) * cc;
    XHh[n * 64 + lane] = hn;
    if (mode == 2) {
        // z = relu(hn @ W1 + b1); pred = z @ W2 + b2
        float z = b1[j];
#pragma unroll
        for (int m = 0; m < 32; ++m)
            z = fmaf(__shfl(hn, jb + m), W1[m * 32 + j], z);
        float pz = fmaxf(z, 0.f) * W2[j];
#pragma unroll
        for (int off = 16; off; off >>= 1) pz += __shfl_xor(pz, off);
        if (j == 0) {
            const float pred = pz + b2[0];
            out[((size_t)b * TT + t_out) * NV + n] = pred;
            XHx[n * 2 + b] = pred;
        }
    } else if (j == 0) {
        XHx[n * 2 + b] = (mode == 0)
            ? x[((size_t)b * TT + t_next) * NV + n] : 0.f;
    }
}

extern "C" void kernel_launch(void* const* d_in, const int* in_sizes, int n_in,
                              void* d_out, int out_size, void* d_ws, size_t ws_size,
                              hipStream_t stream) {
    const float* x      = (const float*)d_in[0];
    // d_in[1] = edge_index (gso already encodes it)
    const float* gso    = (const float*)d_in[2];
    const float* enc_Wr = (const float*)d_in[3];
    const float* enc_br = (const float*)d_in[4];
    const float* enc_Wu = (const float*)d_in[5];
    const float* enc_bu = (const float*)d_in[6];
    const float* enc_Wc = (const float*)d_in[7];
    const float* enc_bc = (const float*)d_in[8];
    const float* dec_Wr = (const float*)d_in[9];
    const float* dec_br = (const float*)d_in[10];
    const float* dec_Wu = (const float*)d_in[11];
    const float* dec_bu = (const float*)d_in[12];
    const float* dec_Wc = (const float*)d_in[13];
    const float* dec_bc = (const float*)d_in[14];
    const float* po_W1  = (const float*)d_in[15];
    const float* po_b1  = (const float*)d_in[16];
    const float* po_W2  = (const float*)d_in[17];
    const float* po_b2  = (const float*)d_in[18];
    float* out = (float*)d_out;

    char* p = (char*)d_ws;
    auto alloc = [&](size_t bytes) {
        char* q = p;
        p += (bytes + 255) & ~(size_t)255;
        return q;
    };
    int*   ellc  = (int*)  alloc((size_t)NV * CAP * 4);
    float* ellv  = (float*)alloc((size_t)NV * CAP * 4);
    int*   rcnt  = (int*)  alloc((size_t)NV * 4);
    int*   rcnt2 = (int*)  alloc((size_t)NV * 4);
    float* XHh   = (float*)alloc((size_t)NV * 64 * 4);
    float* XHx   = (float*)alloc((size_t)NV * 2 * 4);
    float* XCh   = (float*)alloc((size_t)NV * 64 * 4);
    float* XCx   = (float*)alloc((size_t)NV * 2 * 4);
    float* U     = (float*)alloc((size_t)NV * 64 * 4);
    // adaptive S2 capacity: prefer 768 (mean ~306, +6 sigma), fit ws_size
    size_t used = (size_t)(p - (char*)d_ws);
    size_t rem  = ws_size > used ? ws_size - used : 0;
    int cap2 = (int)(rem / ((size_t)NV * 8));
    if (cap2 > 768) cap2 = 768;
    cap2 &= ~63;
    if (cap2 < 64) cap2 = 64;
    int*   ell2c = (int*)  alloc((size_t)NV * cap2 * 4);
    float* ell2v = (float*)alloc((size_t)NV * cap2 * 4);

    const dim3 blk(512);
    const dim3 g_node(NV / 8);    // 1 wave per node, 8 waves/block

    hipLaunchKernelGGL(build_ell, dim3(NV / 4), dim3(256), 0, stream,
                       gso, ellc, ellv, rcnt, XHh, XHx, x);
    hipLaunchKernelGGL(build_s2, g_node, blk, 0, stream,
                       ellc, ellv, rcnt, ell2c, ell2v, rcnt2, cap2);

    // encoder: 24 cells x 2 kernels
    for (int t = 0; t < TT; ++t) {
        hipLaunchKernelGGL(gates_k, g_node, blk, 0, stream,
                           ellc, ellv, rcnt, ell2c, ell2v, rcnt2, cap2,
                           XHh, XHx, enc_Wr, enc_br, enc_Wu, enc_bu,
                           U, XCh, XCx);
        hipLaunchKernelGGL(cand_k, g_node, blk, 0, stream,
                           ellc, ellv, rcnt, ell2c, ell2v, rcnt2, cap2,
                           XCh, XCx, XHh, XHx, U,
                           enc_Wc, enc_bc, x, po_W1, po_b1, po_W2, po_b2,
                           out, (t + 1 < TT) ? 0 : 1, t + 1, 0);
    }
    // decoder: 24 cells x 2 kernels (head fused into cand_k)
    for (int t = 0; t < TT; ++t) {
        hipLaunchKernelGGL(gates_k, g_node, blk, 0, stream,
                           ellc, ellv, rcnt, ell2c, ell2v, rcnt2, cap2,
                           XHh, XHx, dec_Wr, dec_br, dec_Wu, dec_bu,
                           U, XCh, XCx);
        hipLaunchKernelGGL(cand_k, g_node, blk, 0, stream,
                           ellc, ellv, rcnt, ell2c, ell2v, rcnt2, cap2,
                           XCh, XCx, XHh, XHx, U,
                           dec_Wc, dec_bc, x, po_W1, po_b1, po_W2, po_b2,
                           out, 2, 0, t);
    }
}